// Round 5
// baseline (357.215 us; speedup 1.0000x reference)
//
#include <hip/hip_runtime.h>
#include <stdint.h>
#include <stddef.h>

#define NB 2
#define NT 4096
#define NC 768
#define NH 12
#define ND 64

typedef unsigned short u16;
typedef __attribute__((ext_vector_type(4))) float f32x4;
typedef __attribute__((ext_vector_type(16))) float f32x16;
typedef __attribute__((ext_vector_type(8))) unsigned short u16x8;
typedef __attribute__((ext_vector_type(4))) unsigned short u16x4;
typedef __attribute__((ext_vector_type(8))) __bf16 bf16x8;
typedef __attribute__((ext_vector_type(4))) unsigned int u32x4;

__device__ __forceinline__ u16 f2bf(float f) {
  uint32_t u = __builtin_bit_cast(uint32_t, f);
  u += 0x7FFFu + ((u >> 16) & 1u);   // RTNE
  return (u16)(u >> 16);
}
__device__ __forceinline__ bf16x8 asbf(u16x8 v) { return __builtin_bit_cast(bf16x8, v); }

// pack two f32 -> two bf16, round-half-up: 3 VALU
__device__ __forceinline__ uint32_t pkbf(float a, float b) {
  uint32_t ua = __builtin_bit_cast(uint32_t, a) + 0x8000u;
  uint32_t ub = __builtin_bit_cast(uint32_t, b) + 0x8000u;
  return __builtin_amdgcn_perm(ub, ua, 0x07060302u);
}
// truncating pack (P only; numerator/denominator stay consistent): 1 VALU
__device__ __forceinline__ uint32_t pktr(float a, float b) {
  return __builtin_amdgcn_perm(__builtin_bit_cast(uint32_t, b),
                               __builtin_bit_cast(uint32_t, a), 0x07060302u);
}

// ---------------- cast fp32 -> bf16 ----------------
__global__ void k_cast(const float* __restrict__ in, u16* __restrict__ out, int n4) {
  int i = blockIdx.x * blockDim.x + threadIdx.x;
  if (i < n4) {
    f32x4 v = ((const f32x4*)in)[i];
    u16x4 o;
    o[0] = f2bf(v[0]); o[1] = f2bf(v[1]); o[2] = f2bf(v[2]); o[3] = f2bf(v[3]);
    ((u16x4*)out)[i] = o;
  }
}

// -------- transpose + cast --------
__global__ void k_transpose(const float* __restrict__ in, u16* __restrict__ out,
                            int R, int Cn) {
  __shared__ float tile[32][33];
  int c0 = blockIdx.x * 32, r0 = blockIdx.y * 32;
  int tx = threadIdx.x & 31, ty = threadIdx.x >> 5;
  for (int i = ty; i < 32; i += 8)
    tile[i][tx] = in[(size_t)(r0 + i) * Cn + c0 + tx];
  __syncthreads();
  for (int i = ty; i < 32; i += 8)
    out[(size_t)(c0 + i) * R + r0 + tx] = f2bf(tile[tx][i]);
}

// -------- GEMM: C[M,N] = A[M,K] * Bt[N,K]^T --------
template <int EPI>
__global__ __launch_bounds__(256, 2)
void k_gemm_bt(const u16* __restrict__ A, const u16* __restrict__ Bt,
               int M, int N, int K,
               u16* __restrict__ o0, u16* __restrict__ o1, u16* __restrict__ o2,
               float* __restrict__ of) {
  __shared__ u16 As[128 * 40];
  __shared__ u16 Bs[128 * 40];
  const int tid = threadIdx.x;
  const int wave = tid >> 6, lane = tid & 63, quad = lane >> 4, lc = lane & 15;
  const int wm = (wave & 1) * 64, wn = (wave >> 1) * 64;
  const int bm = blockIdx.y * 128, bn = blockIdx.x * 128;

  const int sr = tid >> 2;
  const int sc8 = (tid & 3) * 8;
  const u16* ap0 = A + (size_t)(bm + sr) * K + sc8;
  const u16* ap1 = A + (size_t)(bm + 64 + sr) * K + sc8;
  const u16* bp0 = Bt + (size_t)(bn + sr) * K + sc8;
  const u16* bp1 = Bt + (size_t)(bn + 64 + sr) * K + sc8;
  u16* asl0 = &As[sr * 40 + sc8];
  u16* asl1 = &As[(64 + sr) * 40 + sc8];
  u16* bsl0 = &Bs[sr * 40 + sc8];
  u16* bsl1 = &Bs[(64 + sr) * 40 + sc8];

  f32x4 zv = {0.f, 0.f, 0.f, 0.f};
  f32x4 acc[4][4];
#pragma unroll
  for (int i = 0; i < 4; ++i)
#pragma unroll
    for (int j = 0; j < 4; ++j) acc[i][j] = zv;

  for (int k0 = 0; k0 < K; k0 += 32) {
    u16x8 a0 = *(const u16x8*)(ap0 + k0);
    u16x8 a1 = *(const u16x8*)(ap1 + k0);
    u16x8 b0 = *(const u16x8*)(bp0 + k0);
    u16x8 b1 = *(const u16x8*)(bp1 + k0);
    __syncthreads();
    *(u16x8*)asl0 = a0;
    *(u16x8*)asl1 = a1;
    *(u16x8*)bsl0 = b0;
    *(u16x8*)bsl1 = b1;
    __syncthreads();

    bf16x8 af[4], bfv[4];
#pragma unroll
    for (int mi = 0; mi < 4; ++mi)
      af[mi] = asbf(*(const u16x8*)&As[(wm + mi * 16 + lc) * 40 + quad * 8]);
#pragma unroll
    for (int ni = 0; ni < 4; ++ni)
      bfv[ni] = asbf(*(const u16x8*)&Bs[(wn + ni * 16 + lc) * 40 + quad * 8]);
#pragma unroll
    for (int mi = 0; mi < 4; ++mi)
#pragma unroll
      for (int ni = 0; ni < 4; ++ni)
        acc[mi][ni] = __builtin_amdgcn_mfma_f32_16x16x32_bf16(af[mi], bfv[ni],
                                                              acc[mi][ni], 0, 0, 0);
  }

  const int mrow0 = bm + wm + quad * 4;
#pragma unroll
  for (int mi = 0; mi < 4; ++mi) {
    const int mbase = mrow0 + mi * 16;
#pragma unroll
    for (int ni = 0; ni < 4; ++ni) {
      const int n = bn + wn + ni * 16 + lc;
      if (EPI == 0) {
#pragma unroll
        for (int r = 0; r < 4; ++r)
          of[(size_t)(mbase + r) * N + n] = acc[mi][ni][r];
      } else {
        const int sect = n / NC;          // 0=q 1=k 2=v
        const int wn2 = n - sect * NC;
        const int h = wn2 >> 6, d = wn2 & 63;
        const int b = mbase >> 12;
        const int t = mbase & (NT - 1);
        const float sc = (sect == 0) ? 0.18033688011112042f : 1.0f;  // log2e/8
        if (sect == 2) {
          u16x4 pk;
#pragma unroll
          for (int r = 0; r < 4; ++r) pk[r] = f2bf(acc[mi][ni][r]);
          *(u16x4*)&o2[((size_t)(b * NH + h) * ND + d) * NT + t] = pk;
        } else {
          u16* dst = (sect == 0) ? o0 : o1;
#pragma unroll
          for (int r = 0; r < 4; ++r)
            dst[((size_t)(b * NH + h) * NT + (t + r)) * ND + d] =
                f2bf(acc[mi][ni][r] * sc);
        }
      }
    }
  }
}

// ====== flash attention v5: LDS-free, barrier-free single-wave streaming ====
// K/V (25MB total) is L3-resident (r2 evidence: FETCH 19.5MB), and the ks-loop
// reads full 64B lines -> A-fragments come straight from global through L1/L2.
// No LDS, no staging, no barriers: grid = 1536 one-wave blocks (bh fast-
// varying, qi descending = r2's proven dynamic balance + lockstep tau walk).
// Each wave owns 64 q rows (A/B q-halves share every K/V fragment: 4 loads ->
// 8 MFMAs), walks 64t tiles in two 32t phases; diagonal tile peeled so the
// inner loop is mask-free.  O and the truncated-exp denominator complete
// in-wave (pktr + permlane32_swap + shfl_xor, proven r1-r4) -> the epilogue
// needs no cross-wave combine.  12 independent waves/CU at unsynchronized
// phases overlap the MFMA / VALU / trans / VMEM pipes across waves.

template <bool MSK>
__device__ __forceinline__ void softpackT(const f32x16& s, int l31, int l5,
                                          float& sl, bf16x8* pf) {
  float e[16];
#pragma unroll
  for (int r = 0; r < 16; ++r) {
    float v = s[r];
    if (MSK) {
      int tl = (r & 3) + 8 * (r >> 2) + 4 * l5;   // 32x32 C-layout row (t)
      v = (tl > l31) ? -1e30f : v;
    }
    e[r] = exp2f(v);
    sl += __builtin_bit_cast(float,
          __builtin_bit_cast(uint32_t, e[r]) & 0xFFFF0000u);
  }
  uint32_t wv[8];
#pragma unroll
  for (int i = 0; i < 8; ++i) wv[i] = pktr(e[2 * i], e[2 * i + 1]);
#pragma unroll
  for (int g = 0; g < 2; ++g) {
    auto r0 = __builtin_amdgcn_permlane32_swap(wv[g * 4 + 0], wv[g * 4 + 2], false, false);
    auto r1 = __builtin_amdgcn_permlane32_swap(wv[g * 4 + 1], wv[g * 4 + 3], false, false);
    u32x4 f = {r0[0], r1[0], r0[1], r1[1]};
    pf[g] = __builtin_bit_cast(bf16x8, f);
  }
}

// one 32t x 64q step: Kt -> K rows t..t+32, Vc -> V^T cols t..t+32
template <bool MA, bool MB, bool AA>
__device__ __forceinline__ void tstep(
    const u16* __restrict__ Kt, const u16* __restrict__ Vc,
    int l31, int l5,
    const bf16x8* bqA, const bf16x8* bqB,
    f32x16& oA0, f32x16& oA1, f32x16& oB0, f32x16& oB1,
    float& slA, float& slB, const f32x16& Zv)
{
  const u16* krow = Kt + (size_t)l31 * ND + l5 * 8;
  f32x16 sA = Zv, sB = Zv;
  __builtin_amdgcn_s_setprio(1);
#pragma unroll
  for (int ks = 0; ks < 4; ++ks) {
    bf16x8 kf = asbf(*(const u16x8*)(krow + ks * 16));
    if (AA)
      sA = __builtin_amdgcn_mfma_f32_32x32x16_bf16(kf, bqA[ks], sA, 0, 0, 0);
    sB = __builtin_amdgcn_mfma_f32_32x32x16_bf16(kf, bqB[ks], sB, 0, 0, 0);
  }
  __builtin_amdgcn_s_setprio(0);

  // kp0 V-fragments issued before softpack: their latency hides under it
  const u16* vcol0 = Vc + l5 * 8;
  bf16x8 v00 = asbf(*(const u16x8*)(vcol0 + (size_t)l31 * NT));
  bf16x8 v01 = asbf(*(const u16x8*)(vcol0 + (size_t)(32 + l31) * NT));

  bf16x8 pA[2], pB[2];
  if (AA) softpackT<MA>(sA, l31, l5, slA, pA);
  softpackT<MB>(sB, l31, l5, slB, pB);

  __builtin_amdgcn_s_setprio(1);
  if (AA) {
    oA0 = __builtin_amdgcn_mfma_f32_32x32x16_bf16(v00, pA[0], oA0, 0, 0, 0);
    oA1 = __builtin_amdgcn_mfma_f32_32x32x16_bf16(v01, pA[0], oA1, 0, 0, 0);
  }
  oB0 = __builtin_amdgcn_mfma_f32_32x32x16_bf16(v00, pB[0], oB0, 0, 0, 0);
  oB1 = __builtin_amdgcn_mfma_f32_32x32x16_bf16(v01, pB[0], oB1, 0, 0, 0);
  __builtin_amdgcn_s_setprio(0);

  const u16* vcol1 = vcol0 + 16;
  bf16x8 v10 = asbf(*(const u16x8*)(vcol1 + (size_t)l31 * NT));
  bf16x8 v11 = asbf(*(const u16x8*)(vcol1 + (size_t)(32 + l31) * NT));
  __builtin_amdgcn_s_setprio(1);
  if (AA) {
    oA0 = __builtin_amdgcn_mfma_f32_32x32x16_bf16(v10, pA[1], oA0, 0, 0, 0);
    oA1 = __builtin_amdgcn_mfma_f32_32x32x16_bf16(v11, pA[1], oA1, 0, 0, 0);
  }
  oB0 = __builtin_amdgcn_mfma_f32_32x32x16_bf16(v10, pB[1], oB0, 0, 0, 0);
  oB1 = __builtin_amdgcn_mfma_f32_32x32x16_bf16(v11, pB[1], oB1, 0, 0, 0);
  __builtin_amdgcn_s_setprio(0);
}

__global__ __launch_bounds__(64, 3)
void k_attn(const u16* __restrict__ Q, const u16* __restrict__ K,
            const u16* __restrict__ Vt, u16* __restrict__ Y) {
  const int lane = threadIdx.x;
  const int l5 = lane >> 5, l31 = lane & 31;
  const int bh = blockIdx.x % (NB * NH);
  const int qi = 63 - blockIdx.x / (NB * NH);      // long blocks dispatch first
  const int b = bh / NH, h = bh - b * NH;
  const u16* __restrict__ Qb = Q + (size_t)bh * NT * ND;
  const u16* __restrict__ Kb = K + (size_t)bh * NT * ND;
  const u16* __restrict__ Vb = Vt + (size_t)bh * (size_t)ND * NT;

  const int qgA = qi * 64 + l31;       // q-half A columns
  const int qgB = qgA + 32;            // q-half B columns

  // Q as B-operand frags (col q = l31, k(d) = ks*16 + l5*8 + j); log2e/8 folded
  bf16x8 bqA[4], bqB[4];
#pragma unroll
  for (int ks = 0; ks < 4; ++ks) {
    bqA[ks] = asbf(*(const u16x8*)(Qb + (size_t)qgA * ND + ks * 16 + l5 * 8));
    bqB[ks] = asbf(*(const u16x8*)(Qb + (size_t)qgB * ND + ks * 16 + l5 * 8));
  }

  f32x16 Zv;
#pragma unroll
  for (int i = 0; i < 16; ++i) Zv[i] = 0.f;
  f32x16 oA0 = Zv, oA1 = Zv, oB0 = Zv, oB1 = Zv;   // O^T, d-halves
  float slA = 0.f, slB = 0.f;                       // truncation-consistent l

  // full tiles: both 32t phases unmasked, both q-halves active
#pragma unroll 1
  for (int tau = 0; tau < qi; ++tau) {
    const u16* Kt = Kb + (size_t)tau * 64 * ND;
    const u16* Vc = Vb + tau * 64;
    tstep<false, false, true>(Kt, Vc, l31, l5, bqA, bqB,
                              oA0, oA1, oB0, oB1, slA, slB, Zv);
    tstep<false, false, true>(Kt + (size_t)32 * ND, Vc + 32, l31, l5, bqA, bqB,
                              oA0, oA1, oB0, oB1, slA, slB, Zv);
  }
  // diagonal tile: phase0 {A diag-masked, B full}; phase1 {A above-diag skip,
  // B diag-masked}
  {
    const u16* Kt = Kb + (size_t)qi * 64 * ND;
    const u16* Vc = Vb + qi * 64;
    tstep<true, false, true>(Kt, Vc, l31, l5, bqA, bqB,
                             oA0, oA1, oB0, oB1, slA, slB, Zv);
    tstep<false, true, false>(Kt + (size_t)32 * ND, Vc + 32, l31, l5, bqA, bqB,
                              oA0, oA1, oB0, oB1, slA, slB, Zv);
  }

  // ---- epilogue: combine l5 halves of l, normalize, write Y (in-wave) ----
  const float lA = slA + __shfl_xor(slA, 32);
  const float lB = slB + __shfl_xor(slB, 32);
  const float invA = 1.f / lA, invB = 1.f / lB;
#pragma unroll
  for (int s = 0; s < 2; ++s) {
    const f32x16& x0 = s ? oB0 : oA0;
    const f32x16& x1 = s ? oB1 : oA1;
    const float inv = s ? invB : invA;
    const int qg = s ? qgB : qgA;
    u16* yrow = Y + (size_t)(b * NT + qg) * NC + h * 64;
#pragma unroll
    for (int dh = 0; dh < 2; ++dh) {
      const f32x16& o = dh ? x1 : x0;
#pragma unroll
      for (int rq = 0; rq < 4; ++rq) {
        const int d = dh * 32 + 8 * rq + 4 * l5;
        uint2 w;
        w.x = pkbf(o[rq * 4 + 0] * inv, o[rq * 4 + 1] * inv);
        w.y = pkbf(o[rq * 4 + 2] * inv, o[rq * 4 + 3] * inv);
        *(uint2*)&yrow[d] = w;
      }
    }
  }
}

extern "C" void kernel_launch(void* const* d_in, const int* in_sizes, int n_in,
                              void* d_out, int out_size, void* d_ws, size_t ws_size,
                              hipStream_t stream) {
  (void)in_sizes; (void)n_in; (void)out_size; (void)ws_size;
  const float* x = (const float*)d_in[0];
  const float* w_qkv = (const float*)d_in[1];
  const float* w_out = (const float*)d_in[2];
  float* out = (float*)d_out;

  u16* ws = (u16*)d_ws;
  const size_t XE = (size_t)NB * NT * NC;       // 6291456 elements
  u16* xb  = ws;
  u16* wqT = xb + XE;
  u16* woT = wqT + (size_t)3 * NC * NC;
  u16* Qb  = woT + (size_t)NC * NC;
  u16* Kb  = Qb + XE;
  u16* Vtb = Kb + XE;
  u16* yb  = Vtb + XE;

  k_cast<<<(int)(XE / 4 / 256), 256, 0, stream>>>(x, xb, (int)(XE / 4));
  k_transpose<<<dim3(3 * NC / 32, NC / 32), 256, 0, stream>>>(w_qkv, wqT, NC, 3 * NC);
  k_transpose<<<dim3(NC / 32, NC / 32), 256, 0, stream>>>(w_out, woT, NC, NC);
  k_gemm_bt<1><<<dim3(3 * NC / 128, NB * NT / 128), 256, 0, stream>>>(
      xb, wqT, NB * NT, 3 * NC, NC, Qb, Kb, Vtb, nullptr);
  k_attn<<<dim3(1536), 64, 0, stream>>>(Qb, Kb, Vtb, yb);
  k_gemm_bt<0><<<dim3(NC / 128, NB * NT / 128), 256, 0, stream>>>(
      yb, woT, NB * NT, NC, NC, nullptr, nullptr, nullptr, out);
}

// Round 6
// 244.306 us; speedup vs baseline: 1.4622x; 1.4622x over previous
//
#include <hip/hip_runtime.h>
#include <stdint.h>
#include <stddef.h>

#define NB 2
#define NT 4096
#define NC 768
#define NH 12
#define ND 64

typedef unsigned short u16;
typedef __attribute__((ext_vector_type(4))) float f32x4;
typedef __attribute__((ext_vector_type(16))) float f32x16;
typedef __attribute__((ext_vector_type(8))) unsigned short u16x8;
typedef __attribute__((ext_vector_type(4))) unsigned short u16x4;
typedef __attribute__((ext_vector_type(8))) __bf16 bf16x8;
typedef __attribute__((ext_vector_type(4))) unsigned int u32x4;

typedef __attribute__((address_space(1))) const unsigned int gu32;
typedef __attribute__((address_space(3))) unsigned int lu32;

__device__ __forceinline__ u16 f2bf(float f) {
  uint32_t u = __builtin_bit_cast(uint32_t, f);
  u += 0x7FFFu + ((u >> 16) & 1u);   // RTNE
  return (u16)(u >> 16);
}
__device__ __forceinline__ bf16x8 asbf(u16x8 v) { return __builtin_bit_cast(bf16x8, v); }

// pack two f32 -> two bf16, round-half-up: 3 VALU
__device__ __forceinline__ uint32_t pkbf(float a, float b) {
  uint32_t ua = __builtin_bit_cast(uint32_t, a) + 0x8000u;
  uint32_t ub = __builtin_bit_cast(uint32_t, b) + 0x8000u;
  return __builtin_amdgcn_perm(ub, ua, 0x07060302u);
}
// truncating pack (P only; numerator/denominator stay consistent): 1 VALU
__device__ __forceinline__ uint32_t pktr(float a, float b) {
  return __builtin_amdgcn_perm(__builtin_bit_cast(uint32_t, b),
                               __builtin_bit_cast(uint32_t, a), 0x07060302u);
}

#define GLDS(gsrc, ldst) __builtin_amdgcn_global_load_lds( \
    (gu32*)(gsrc), (lu32*)(ldst), 16, 0, 0)

// ---------------- cast fp32 -> bf16 ----------------
__global__ void k_cast(const float* __restrict__ in, u16* __restrict__ out, int n4) {
  int i = blockIdx.x * blockDim.x + threadIdx.x;
  if (i < n4) {
    f32x4 v = ((const f32x4*)in)[i];
    u16x4 o;
    o[0] = f2bf(v[0]); o[1] = f2bf(v[1]); o[2] = f2bf(v[2]); o[3] = f2bf(v[3]);
    ((u16x4*)out)[i] = o;
  }
}

// -------- transpose + cast --------
__global__ void k_transpose(const float* __restrict__ in, u16* __restrict__ out,
                            int R, int Cn) {
  __shared__ float tile[32][33];
  int c0 = blockIdx.x * 32, r0 = blockIdx.y * 32;
  int tx = threadIdx.x & 31, ty = threadIdx.x >> 5;
  for (int i = ty; i < 32; i += 8)
    tile[i][tx] = in[(size_t)(r0 + i) * Cn + c0 + tx];
  __syncthreads();
  for (int i = ty; i < 32; i += 8)
    out[(size_t)(c0 + i) * R + r0 + tx] = f2bf(tile[tx][i]);
}

// -------- GEMM: C[M,N] = A[M,K] * Bt[N,K]^T  (m97 structure) --------
// Staging via global_load_lds dwordx4 into LINEAR LDS (no pad; GLDS writes
// wave-uniform base + lane*16B, which equals As[sr*32+sc8] here). One
// vmcnt(0)+barrier pair per K-step (m97's proven 2-barrier loop). The
// stride-32 frag reads carry the known m97 bank-conflict cost (m98: still
// 874 TF at 4096^3). Epilogue/acc layout untouched from the verified version.
template <int EPI>
__global__ __launch_bounds__(256, 3)
void k_gemm_bt(const u16* __restrict__ A, const u16* __restrict__ Bt,
               int M, int N, int K,
               u16* __restrict__ o0, u16* __restrict__ o1, u16* __restrict__ o2,
               float* __restrict__ of) {
  __shared__ u16 As[128 * 32];
  __shared__ u16 Bs[128 * 32];
  const int tid = threadIdx.x;
  const int wave = tid >> 6, lane = tid & 63, quad = lane >> 4, lc = lane & 15;
  const int wm = (wave & 1) * 64, wn = (wave >> 1) * 64;
  const int bm = blockIdx.y * 128, bn = blockIdx.x * 128;

  const int sr = tid >> 2;          // 0..63
  const int sc8 = (tid & 3) * 8;    // K-chunk
  const u16* ga0 = A + (size_t)(bm + sr) * K + sc8;
  const u16* ga1 = A + (size_t)(bm + 64 + sr) * K + sc8;
  const u16* gb0 = Bt + (size_t)(bn + sr) * K + sc8;
  const u16* gb1 = Bt + (size_t)(bn + 64 + sr) * K + sc8;
  // wave-uniform LDS bases; HW writes lane l at +l*16B = [sr*32 + sc8]
  u16* la0 = &As[wave * 512];
  u16* la1 = &As[2048 + wave * 512];
  u16* lb0 = &Bs[wave * 512];
  u16* lb1 = &Bs[2048 + wave * 512];

  f32x4 zv = {0.f, 0.f, 0.f, 0.f};
  f32x4 acc[4][4];
#pragma unroll
  for (int i = 0; i < 4; ++i)
#pragma unroll
    for (int j = 0; j < 4; ++j) acc[i][j] = zv;

  for (int k0 = 0; k0 < K; k0 += 32) {
    __syncthreads();                 // prev iter's frag reads complete
    GLDS(ga0 + k0, la0);
    GLDS(ga1 + k0, la1);
    GLDS(gb0 + k0, lb0);
    GLDS(gb1 + k0, lb1);
    asm volatile("s_waitcnt vmcnt(0)" ::: "memory");
    __syncthreads();                 // all waves' DMA landed

    bf16x8 af[4], bfv[4];
#pragma unroll
    for (int mi = 0; mi < 4; ++mi)
      af[mi] = asbf(*(const u16x8*)&As[(wm + mi * 16 + lc) * 32 + quad * 8]);
#pragma unroll
    for (int ni = 0; ni < 4; ++ni)
      bfv[ni] = asbf(*(const u16x8*)&Bs[(wn + ni * 16 + lc) * 32 + quad * 8]);
#pragma unroll
    for (int mi = 0; mi < 4; ++mi)
#pragma unroll
      for (int ni = 0; ni < 4; ++ni)
        acc[mi][ni] = __builtin_amdgcn_mfma_f32_16x16x32_bf16(af[mi], bfv[ni],
                                                              acc[mi][ni], 0, 0, 0);
  }

  const int mrow0 = bm + wm + quad * 4;
#pragma unroll
  for (int mi = 0; mi < 4; ++mi) {
    const int mbase = mrow0 + mi * 16;
#pragma unroll
    for (int ni = 0; ni < 4; ++ni) {
      const int n = bn + wn + ni * 16 + lc;
      if (EPI == 0) {
#pragma unroll
        for (int r = 0; r < 4; ++r)
          of[(size_t)(mbase + r) * N + n] = acc[mi][ni][r];
      } else {
        const int sect = n / NC;          // 0=q 1=k 2=v
        const int wn2 = n - sect * NC;
        const int h = wn2 >> 6, d = wn2 & 63;
        const int b = mbase >> 12;
        const int t = mbase & (NT - 1);
        const float sc = (sect == 0) ? 0.18033688011112042f : 1.0f;  // log2e/8
        if (sect == 2) {
          u16x4 pk;
#pragma unroll
          for (int r = 0; r < 4; ++r) pk[r] = f2bf(acc[mi][ni][r]);
          *(u16x4*)&o2[((size_t)(b * NH + h) * ND + d) * NT + t] = pk;
        } else {
          u16* dst = (sect == 0) ? o0 : o1;
#pragma unroll
          for (int r = 0; r < 4; ++r)
            dst[((size_t)(b * NH + h) * NT + (t + r)) * ND + d] =
                f2bf(acc[mi][ni][r] * sc);
        }
      }
    }
  }
}

// ============ flash attention (r2, verbatim): causal, 32x32x16, wave-split ==
// Grid = 24 bh x 64 q-tiles (descending qi: long blocks dispatch first).
// Block = 4 waves (qh = wave&1, th = wave>>1): each wave computes a 32q x 32t
// sub-tile per K/V tile.  No online rescale => t-tiles independent => th-pair
// waves hold partial O/l in registers and combine ONCE via LDS at epilogue.
// P stays in registers: S^T cols are lane-local (32x32 C layout), repacked to
// the PV B-operand with pktr + permlane32_swap.
// LDS: single 16KB K/V tile, XOR-swizzled (granule ^= row&7), reused as the
// epilogue park area.  Denominator = in-lane sum of TRUNCATED exp (consistent
// with bf16 P) + shfl_xor(32) + cross-wave add.
__device__ __forceinline__ void softpack16(const f32x16& s, int qrel, bool msk,
                                           int l5, float& sl, bf16x8* pf) {
  float e[16];
#pragma unroll
  for (int r = 0; r < 16; ++r) {
    float v = s[r];
    if (msk) {
      int tl = (r & 3) + 8 * (r >> 2) + 4 * l5;   // 32x32 C-layout row
      v = (tl > qrel) ? -1e30f : v;
    }
    e[r] = exp2f(v);
    sl += __builtin_bit_cast(float,
          __builtin_bit_cast(uint32_t, e[r]) & 0xFFFF0000u);
  }
  uint32_t wv[8];
#pragma unroll
  for (int i = 0; i < 8; ++i) wv[i] = pktr(e[2 * i], e[2 * i + 1]);
  // B-frag g covers t_local = g*16 + l5*8 + j; half-exchange = permlane32_swap
#pragma unroll
  for (int g = 0; g < 2; ++g) {
    auto r0 = __builtin_amdgcn_permlane32_swap(wv[g * 4 + 0], wv[g * 4 + 2], false, false);
    auto r1 = __builtin_amdgcn_permlane32_swap(wv[g * 4 + 1], wv[g * 4 + 3], false, false);
    u32x4 f = {r0[0], r1[0], r0[1], r1[1]};
    pf[g] = __builtin_bit_cast(bf16x8, f);
  }
}

__global__ __launch_bounds__(256, 3)
void k_attn(const u16* __restrict__ Q, const u16* __restrict__ K,
            const u16* __restrict__ Vt, u16* __restrict__ Y) {
  __shared__ u16 SM[2][64 * 64];   // [0]=K tile [t][d], [1]=V^T tile [d][t]
  __shared__ float PL[2][64];      // l park
  const int tid = threadIdx.x;
  const int lane = tid & 63, wave = tid >> 6;
  const int l5 = lane >> 5, l31 = lane & 31;
  const int qh = wave & 1, th = wave >> 1;
  const int bh = blockIdx.x % (NB * NH);
  const int qi = 63 - blockIdx.x / (NB * NH);      // long blocks first
  const int b = bh / NH, h = bh - b * NH;
  const u16* __restrict__ Qb = Q + (size_t)bh * NT * ND;
  const u16* __restrict__ Kb = K + (size_t)bh * NT * ND;
  const u16* __restrict__ Vb = Vt + (size_t)bh * (size_t)ND * NT;

  const int qg = qi * 64 + qh * 32 + l31;          // this lane's q column

  // Q as B-operand frags: col q = l31(+qh*32), k(d) = ks*16 + l5*8 + j
  bf16x8 bq[4];
#pragma unroll
  for (int ks = 0; ks < 4; ++ks)
    bq[ks] = asbf(*(const u16x8*)(Qb + (size_t)qg * ND + ks * 16 + l5 * 8));

  f32x16 Zv;
#pragma unroll
  for (int i = 0; i < 16; ++i) Zv[i] = 0.f;
  f32x16 o0 = Zv, o1 = Zv;     // O^T partial (d-halves), this wave's (qh,th)
  float sl = 0.f;              // truncation-consistent partial l

  // staging: 256 thr x 4 x 16B = 16KB/iter; dest XOR-swizzled
  const int srow = tid >> 3, sg = tid & 7;
  const int soff = srow * 64 + ((sg ^ (srow & 7)) * 8);
  const u16* __restrict__ pK = Kb + (size_t)srow * ND + sg * 8;
  const u16* __restrict__ pV = Vb + (size_t)srow * NT + sg * 8;

  // LDS frag offsets (elements), matching XOR swizzle
  int qfro[4];
#pragma unroll
  for (int ks = 0; ks < 4; ++ks)
    qfro[ks] = (th * 32 + l31) * 64 + (((ks * 2 + l5) ^ (l31 & 7)) * 8);
  int vfro[2];
#pragma unroll
  for (int kp = 0; kp < 2; ++kp)
    vfro[kp] = l31 * 64 + ((((2 * th + kp) * 2 + l5) ^ (l31 & 7)) * 8);

  // prefetch tile 0
  u16x8 st[4];
  st[0] = *(const u16x8*)(pK);
  st[1] = *(const u16x8*)(pK + (size_t)32 * ND);
  st[2] = *(const u16x8*)(pV);
  st[3] = *(const u16x8*)(pV + (size_t)32 * NT);

#pragma unroll 1
  for (int tau = 0; tau <= qi; ++tau) {
    __syncthreads();
    *(u16x8*)&SM[0][soff] = st[0];
    *(u16x8*)&SM[0][2048 + soff] = st[1];
    *(u16x8*)&SM[1][soff] = st[2];
    *(u16x8*)&SM[1][2048 + soff] = st[3];
    __syncthreads();

    const bool dg = (tau == qi);
    const bool act = !(dg && th > qh);    // wave-uniform
    bf16x8 p[2];
    if (act) {
      // S^T[32t x 32q] = K(th half) Q(qh)^T
      f32x16 s = Zv;
#pragma unroll
      for (int ks = 0; ks < 4; ++ks) {
        bf16x8 kf = asbf(*(const u16x8*)&SM[0][qfro[ks]]);
        s = __builtin_amdgcn_mfma_f32_32x32x16_bf16(kf, bq[ks], s, 0, 0, 0);
      }
      softpack16(s, l31, dg && (th == qh), l5, sl, p);
    }

    // prefetch next tile (all threads; hides HBM latency under PV)
    if (tau < qi) {
      const int tn = (tau + 1) * 64;
      st[0] = *(const u16x8*)(pK + (size_t)tn * ND);
      st[1] = *(const u16x8*)(pK + (size_t)(tn + 32) * ND);
      st[2] = *(const u16x8*)(pV + tn);
      st[3] = *(const u16x8*)(pV + (size_t)32 * NT + tn);
    }

    if (act) {
      // O^T += V^T(d-halves) P^T(this wave's t-slice)
#pragma unroll
      for (int kp = 0; kp < 2; ++kp) {
        bf16x8 v0 = asbf(*(const u16x8*)&SM[1][vfro[kp]]);
        bf16x8 v1 = asbf(*(const u16x8*)&SM[1][2048 + vfro[kp]]);
        o0 = __builtin_amdgcn_mfma_f32_32x32x16_bf16(v0, p[kp], o0, 0, 0, 0);
        o1 = __builtin_amdgcn_mfma_f32_32x32x16_bf16(v1, p[kp], o1, 0, 0, 0);
      }
    }
  }

  // ---- epilogue: combine l5 halves, then th-pair waves via LDS park ----
  float l = sl + __shfl_xor(sl, 32);
  __syncthreads();                       // done reading SM as K/V
  float* PK = (float*)&SM[0][0];         // 16KB park: [64 rows][64 lanes] f32
  if (th == 0) {
#pragma unroll
    for (int r = 0; r < 16; ++r) PK[(qh * 32 + r) * 64 + lane] = o0[r];
#pragma unroll
    for (int r = 0; r < 16; ++r) PK[(qh * 32 + 16 + r) * 64 + lane] = o1[r];
    PL[qh][lane] = l;
  }
  __syncthreads();
  if (th == 1) {
#pragma unroll
    for (int r = 0; r < 16; ++r) o0[r] += PK[(qh * 32 + r) * 64 + lane];
#pragma unroll
    for (int r = 0; r < 16; ++r) o1[r] += PK[(qh * 32 + 16 + r) * 64 + lane];
    l += PL[qh][lane];
    const float inv = 1.f / l;
    u16* yrow = Y + (size_t)(b * NT + qg) * NC + h * 64;
#pragma unroll
    for (int dh = 0; dh < 2; ++dh) {
      const f32x16& o = dh ? o1 : o0;
#pragma unroll
      for (int rq = 0; rq < 4; ++rq) {
        const int d = dh * 32 + 8 * rq + 4 * l5;
        uint2 w;
        w.x = pkbf(o[rq * 4 + 0] * inv, o[rq * 4 + 1] * inv);
        w.y = pkbf(o[rq * 4 + 2] * inv, o[rq * 4 + 3] * inv);
        *(uint2*)&yrow[d] = w;
      }
    }
  }
}

extern "C" void kernel_launch(void* const* d_in, const int* in_sizes, int n_in,
                              void* d_out, int out_size, void* d_ws, size_t ws_size,
                              hipStream_t stream) {
  (void)in_sizes; (void)n_in; (void)out_size; (void)ws_size;
  const float* x = (const float*)d_in[0];
  const float* w_qkv = (const float*)d_in[1];
  const float* w_out = (const float*)d_in[2];
  float* out = (float*)d_out;

  u16* ws = (u16*)d_ws;
  const size_t XE = (size_t)NB * NT * NC;       // 6291456 elements
  u16* xb  = ws;
  u16* wqT = xb + XE;
  u16* woT = wqT + (size_t)3 * NC * NC;
  u16* Qb  = woT + (size_t)NC * NC;
  u16* Kb  = Qb + XE;
  u16* Vtb = Kb + XE;
  u16* yb  = Vtb + XE;

  k_cast<<<(int)(XE / 4 / 256), 256, 0, stream>>>(x, xb, (int)(XE / 4));
  k_transpose<<<dim3(3 * NC / 32, NC / 32), 256, 0, stream>>>(w_qkv, wqT, NC, 3 * NC);
  k_transpose<<<dim3(NC / 32, NC / 32), 256, 0, stream>>>(w_out, woT, NC, NC);
  k_gemm_bt<1><<<dim3(3 * NC / 128, NB * NT / 128), 256, 0, stream>>>(
      xb, wqT, NB * NT, 3 * NC, NC, Qb, Kb, Vtb, nullptr);
  k_attn<<<dim3((NB * NH) * 64), 256, 0, stream>>>(Qb, Kb, Vtb, yb);
  k_gemm_bt<0><<<dim3(NC / 128, NB * NT / 128), 256, 0, stream>>>(
      yb, woT, NB * NT, NC, NC, nullptr, nullptr, nullptr, out);
}

// Round 7
// 235.286 us; speedup vs baseline: 1.5182x; 1.0383x over previous
//
#include <hip/hip_runtime.h>
#include <stdint.h>
#include <stddef.h>

#define NB 2
#define NT 4096
#define NC 768
#define NH 12
#define ND 64

typedef unsigned short u16;
typedef __attribute__((ext_vector_type(2))) float f32x2;
typedef __attribute__((ext_vector_type(4))) float f32x4;
typedef __attribute__((ext_vector_type(16))) float f32x16;
typedef __attribute__((ext_vector_type(8))) unsigned short u16x8;
typedef __attribute__((ext_vector_type(4))) unsigned short u16x4;
typedef __attribute__((ext_vector_type(8))) __bf16 bf16x8;
typedef __attribute__((ext_vector_type(4))) unsigned int u32x4;

typedef __attribute__((address_space(1))) const unsigned int gu32;
typedef __attribute__((address_space(3))) unsigned int lu32;

__device__ __forceinline__ u16 f2bf(float f) {
  uint32_t u = __builtin_bit_cast(uint32_t, f);
  u += 0x7FFFu + ((u >> 16) & 1u);   // RTNE
  return (u16)(u >> 16);
}
__device__ __forceinline__ bf16x8 asbf(u16x8 v) { return __builtin_bit_cast(bf16x8, v); }

// pack two f32 -> two bf16, round-half-up: 3 VALU
__device__ __forceinline__ uint32_t pkbf(float a, float b) {
  uint32_t ua = __builtin_bit_cast(uint32_t, a) + 0x8000u;
  uint32_t ub = __builtin_bit_cast(uint32_t, b) + 0x8000u;
  return __builtin_amdgcn_perm(ub, ua, 0x07060302u);
}
// truncating pack (P only; numerator/denominator stay consistent): 1 VALU
__device__ __forceinline__ uint32_t pktr(float a, float b) {
  return __builtin_amdgcn_perm(__builtin_bit_cast(uint32_t, b),
                               __builtin_bit_cast(uint32_t, a), 0x07060302u);
}

#define GLDS(gsrc, ldst) __builtin_amdgcn_global_load_lds( \
    (gu32*)(gsrc), (lu32*)(ldst), 16, 0, 0)

// ------- merged preprocessing: cast(x) + transpose(w_qkv) + transpose(w_out)
// one launch instead of three (the three are independent, block-uniform split).
#define PRE_CAST_BLKS 6144             // (NB*NT*NC/4)/256
#define PRE_TA_BX 72                   // 3*NC/32
#define PRE_TA_BLKS (72 * 24)
#define PRE_TB_BX 24                   // NC/32
#define PRE_TB_BLKS (24 * 24)
__global__ __launch_bounds__(256)
void k_pre(const float* __restrict__ x, u16* __restrict__ xb,
           const float* __restrict__ w_qkv, u16* __restrict__ wqT,
           const float* __restrict__ w_out, u16* __restrict__ woT) {
  __shared__ float tile[32][33];
  const int bid = blockIdx.x;
  const int tid = threadIdx.x;
  if (bid < PRE_CAST_BLKS) {
    int i = bid * 256 + tid;
    f32x4 v = ((const f32x4*)x)[i];
    u16x4 o;
    o[0] = f2bf(v[0]); o[1] = f2bf(v[1]); o[2] = f2bf(v[2]); o[3] = f2bf(v[3]);
    ((u16x4*)xb)[i] = o;
    return;
  }
  const float* in;
  u16* out;
  int R, Cn, bx, by;
  if (bid < PRE_CAST_BLKS + PRE_TA_BLKS) {
    int q = bid - PRE_CAST_BLKS;
    bx = q % PRE_TA_BX; by = q / PRE_TA_BX;
    in = w_qkv; out = wqT; R = NC; Cn = 3 * NC;
  } else {
    int q = bid - PRE_CAST_BLKS - PRE_TA_BLKS;
    bx = q % PRE_TB_BX; by = q / PRE_TB_BX;
    in = w_out; out = woT; R = NC; Cn = NC;
  }
  int c0 = bx * 32, r0 = by * 32;
  int tx = tid & 31, ty = tid >> 5;
  for (int i = ty; i < 32; i += 8)
    tile[i][tx] = in[(size_t)(r0 + i) * Cn + c0 + tx];
  __syncthreads();
  for (int i = ty; i < 32; i += 8)
    out[(size_t)(c0 + i) * R + r0 + tx] = f2bf(tile[tx][i]);
}

// -------- GEMM: C[M,N] = A[M,K] * Bt[N,K]^T  (m97 structure) --------
// Staging via global_load_lds dwordx4 into LINEAR LDS (GLDS writes wave-
// uniform base + lane*16B = SMEM[sr*32+sc8]).  One vmcnt(0)+barrier pair per
// K-step (m97's proven 2-barrier loop).  EPI==1 V-section (block-uniform:
// 128-col tiles never straddle the 768-wide qkv sections) transposes through
// SMEM (XOR swizzle m^=(nl&7)<<3, bijective, 2-way-free writes) and stores
// V^T as coalesced 256B segments instead of 8B-at-8KB-stride scatter.
template <int EPI>
__global__ __launch_bounds__(256, 3)
void k_gemm_bt(const u16* __restrict__ A, const u16* __restrict__ Bt,
               int M, int N, int K,
               u16* __restrict__ o0, u16* __restrict__ o1, u16* __restrict__ o2,
               float* __restrict__ of) {
  __shared__ u16 SMEM[2 * 128 * 32];   // As | Bs ; reused as transpose buffer
  u16* As = SMEM;
  u16* Bs = SMEM + 4096;
  const int tid = threadIdx.x;
  const int wave = tid >> 6, lane = tid & 63, quad = lane >> 4, lc = lane & 15;
  const int wm = (wave & 1) * 64, wn = (wave >> 1) * 64;
  const int bm = blockIdx.y * 128, bn = blockIdx.x * 128;

  const int sr = tid >> 2;          // 0..63
  const int sc8 = (tid & 3) * 8;    // K-chunk
  const u16* ga0 = A + (size_t)(bm + sr) * K + sc8;
  const u16* ga1 = A + (size_t)(bm + 64 + sr) * K + sc8;
  const u16* gb0 = Bt + (size_t)(bn + sr) * K + sc8;
  const u16* gb1 = Bt + (size_t)(bn + 64 + sr) * K + sc8;
  // wave-uniform LDS bases; HW writes lane l at +l*16B = [sr*32 + sc8]
  u16* la0 = &As[wave * 512];
  u16* la1 = &As[2048 + wave * 512];
  u16* lb0 = &Bs[wave * 512];
  u16* lb1 = &Bs[2048 + wave * 512];

  f32x4 zv = {0.f, 0.f, 0.f, 0.f};
  f32x4 acc[4][4];
#pragma unroll
  for (int i = 0; i < 4; ++i)
#pragma unroll
    for (int j = 0; j < 4; ++j) acc[i][j] = zv;

  for (int k0 = 0; k0 < K; k0 += 32) {
    __syncthreads();                 // prev iter's frag reads complete
    GLDS(ga0 + k0, la0);
    GLDS(ga1 + k0, la1);
    GLDS(gb0 + k0, lb0);
    GLDS(gb1 + k0, lb1);
    asm volatile("s_waitcnt vmcnt(0)" ::: "memory");
    __syncthreads();                 // all waves' DMA landed

    bf16x8 af[4], bfv[4];
#pragma unroll
    for (int mi = 0; mi < 4; ++mi)
      af[mi] = asbf(*(const u16x8*)&As[(wm + mi * 16 + lc) * 32 + quad * 8]);
#pragma unroll
    for (int ni = 0; ni < 4; ++ni)
      bfv[ni] = asbf(*(const u16x8*)&Bs[(wn + ni * 16 + lc) * 32 + quad * 8]);
#pragma unroll
    for (int mi = 0; mi < 4; ++mi)
#pragma unroll
      for (int ni = 0; ni < 4; ++ni)
        acc[mi][ni] = __builtin_amdgcn_mfma_f32_16x16x32_bf16(af[mi], bfv[ni],
                                                              acc[mi][ni], 0, 0, 0);
  }

  const int sect = (EPI == 1) ? (bn / NC) : 0;   // block-uniform
  if (EPI == 1 && sect == 2) {
    // ---- V^T transposed epilogue through SMEM ----
    const int b = bm >> 12;
    const int tb = bm & (NT - 1);
    const int hb = (bn - 2 * NC) >> 6;
#pragma unroll 1
    for (int r2_ = 0; r2_ < 2; ++r2_) {
      __syncthreads();               // SMEM free / prev half read out
      if ((wave >> 1) == r2_) {      // waves owning wn == 64*r2_
#pragma unroll
        for (int mi = 0; mi < 4; ++mi)
#pragma unroll
          for (int ni = 0; ni < 4; ++ni) {
            const int nl = ni * 16 + lc;          // n within this 64-col half
#pragma unroll
            for (int r = 0; r < 4; ++r) {
              const int m = wm + mi * 16 + quad * 4 + r;
              SMEM[nl * 128 + (m ^ ((nl & 7) << 3))] = f2bf(acc[mi][ni][r]);
            }
          }
      }
      __syncthreads();
#pragma unroll
      for (int pass = 0; pass < 4; ++pass) {
        const int row = (tid >> 4) + 16 * pass;   // d-row within half
        const int chunk = tid & 15;               // 8-elem t-chunk
        u16x8 w = *(const u16x8*)&SMEM[row * 128 + ((chunk ^ (row & 7)) * 8)];
        const int nl = 64 * r2_ + row;
        *(u16x8*)&o2[((size_t)(b * NH + hb + (nl >> 6)) * ND + (nl & 63)) * NT
                     + tb + chunk * 8] = w;
      }
    }
    return;
  }

  const int mrow0 = bm + wm + quad * 4;
#pragma unroll
  for (int mi = 0; mi < 4; ++mi) {
    const int mbase = mrow0 + mi * 16;
#pragma unroll
    for (int ni = 0; ni < 4; ++ni) {
      const int n = bn + wn + ni * 16 + lc;
      if (EPI == 0) {
#pragma unroll
        for (int r = 0; r < 4; ++r)
          of[(size_t)(mbase + r) * N + n] = acc[mi][ni][r];
      } else {
        const int wn2 = n - sect * NC;
        const int h = wn2 >> 6, d = wn2 & 63;
        const int b = mbase >> 12;
        const int t = mbase & (NT - 1);
        const float sc = (sect == 0) ? 0.18033688011112042f : 1.0f;  // log2e/8
        u16* dst = (sect == 0) ? o0 : o1;
#pragma unroll
        for (int r = 0; r < 4; ++r)
          dst[((size_t)(b * NH + h) * NT + (t + r)) * ND + d] =
              f2bf(acc[mi][ni][r] * sc);
      }
    }
  }
}

// ============ flash attention (r2 structure): causal, 32x32x16, wave-split ==
// Grid = 24 bh x 64 q-tiles (descending qi: long blocks dispatch first).
// Block = 4 waves (qh = wave&1, th = wave>>1): each wave computes a 32q x 32t
// sub-tile per K/V tile.  No online rescale => t-tiles independent => th-pair
// waves hold partial O/l in registers and combine ONCE via LDS at epilogue.
// P stays in registers: S^T cols are lane-local (32x32 C layout), repacked to
// the PV B-operand with pktr + permlane32_swap.
// LDS: single 16KB K/V tile, XOR-swizzled (granule ^= row&7), reused as the
// epilogue park area.  Denominator = in-lane sum of TRUNCATED exp (consistent
// with bf16 P) kept as a 2-lane partial (packed-add friendly) + shfl_xor(32)
// + cross-wave add.  This round: QK's first MFMA takes the persistent Zv as C
// (kills 16 v_mov/wave-tau) and MFMA clusters run under s_setprio(1) (T5).
__device__ __forceinline__ void softpack16(const f32x16& s, int qrel, bool msk,
                                           int l5, f32x2& sl2, bf16x8* pf) {
  float e[16];
#pragma unroll
  for (int r = 0; r < 16; ++r) {
    float v = s[r];
    if (msk) {
      int tl = (r & 3) + 8 * (r >> 2) + 4 * l5;   // 32x32 C-layout row
      v = (tl > qrel) ? -1e30f : v;
    }
    e[r] = exp2f(v);
  }
  uint32_t wv[8];
#pragma unroll
  for (int i = 0; i < 8; ++i) {
    wv[i] = pktr(e[2 * i], e[2 * i + 1]);
    // denominator from the SAME truncated bf16 values the numerator uses
    f32x2 inc = {__builtin_bit_cast(float, wv[i] & 0xFFFF0000u),
                 __builtin_bit_cast(float, wv[i] << 16)};
    sl2 += inc;
  }
  // B-frag g covers t_local = g*16 + l5*8 + j; half-exchange = permlane32_swap
#pragma unroll
  for (int g = 0; g < 2; ++g) {
    auto r0 = __builtin_amdgcn_permlane32_swap(wv[g * 4 + 0], wv[g * 4 + 2], false, false);
    auto r1 = __builtin_amdgcn_permlane32_swap(wv[g * 4 + 1], wv[g * 4 + 3], false, false);
    u32x4 f = {r0[0], r1[0], r0[1], r1[1]};
    pf[g] = __builtin_bit_cast(bf16x8, f);
  }
}

__global__ __launch_bounds__(256, 3)
void k_attn(const u16* __restrict__ Q, const u16* __restrict__ K,
            const u16* __restrict__ Vt, u16* __restrict__ Y) {
  __shared__ u16 SM[2][64 * 64];   // [0]=K tile [t][d], [1]=V^T tile [d][t]
  __shared__ float PL[2][64];      // l park
  const int tid = threadIdx.x;
  const int lane = tid & 63, wave = tid >> 6;
  const int l5 = lane >> 5, l31 = lane & 31;
  const int qh = wave & 1, th = wave >> 1;
  const int bh = blockIdx.x % (NB * NH);
  const int qi = 63 - blockIdx.x / (NB * NH);      // long blocks first
  const int b = bh / NH, h = bh - b * NH;
  const u16* __restrict__ Qb = Q + (size_t)bh * NT * ND;
  const u16* __restrict__ Kb = K + (size_t)bh * NT * ND;
  const u16* __restrict__ Vb = Vt + (size_t)bh * (size_t)ND * NT;

  const int qg = qi * 64 + qh * 32 + l31;          // this lane's q column

  // Q as B-operand frags: col q = l31(+qh*32), k(d) = ks*16 + l5*8 + j
  bf16x8 bq[4];
#pragma unroll
  for (int ks = 0; ks < 4; ++ks)
    bq[ks] = asbf(*(const u16x8*)(Qb + (size_t)qg * ND + ks * 16 + l5 * 8));

  f32x16 Zv;
#pragma unroll
  for (int i = 0; i < 16; ++i) Zv[i] = 0.f;
  f32x16 o0 = Zv, o1 = Zv;     // O^T partial (d-halves), this wave's (qh,th)
  f32x2 sl2 = {0.f, 0.f};      // truncation-consistent partial l (2 lanes)

  // staging: 256 thr x 4 x 16B = 16KB/iter; dest XOR-swizzled
  const int srow = tid >> 3, sg = tid & 7;
  const int soff = srow * 64 + ((sg ^ (srow & 7)) * 8);
  const u16* __restrict__ pK = Kb + (size_t)srow * ND + sg * 8;
  const u16* __restrict__ pV = Vb + (size_t)srow * NT + sg * 8;

  // LDS frag offsets (elements), matching XOR swizzle
  int qfro[4];
#pragma unroll
  for (int ks = 0; ks < 4; ++ks)
    qfro[ks] = (th * 32 + l31) * 64 + (((ks * 2 + l5) ^ (l31 & 7)) * 8);
  int vfro[2];
#pragma unroll
  for (int kp = 0; kp < 2; ++kp)
    vfro[kp] = l31 * 64 + ((((2 * th + kp) * 2 + l5) ^ (l31 & 7)) * 8);

  // prefetch tile 0
  u16x8 st[4];
  st[0] = *(const u16x8*)(pK);
  st[1] = *(const u16x8*)(pK + (size_t)32 * ND);
  st[2] = *(const u16x8*)(pV);
  st[3] = *(const u16x8*)(pV + (size_t)32 * NT);

#pragma unroll 1
  for (int tau = 0; tau <= qi; ++tau) {
    __syncthreads();
    *(u16x8*)&SM[0][soff] = st[0];
    *(u16x8*)&SM[0][2048 + soff] = st[1];
    *(u16x8*)&SM[1][soff] = st[2];
    *(u16x8*)&SM[1][2048 + soff] = st[3];
    __syncthreads();

    const bool dg = (tau == qi);
    const bool act = !(dg && th > qh);    // wave-uniform
    bf16x8 p[2];
    if (act) {
      // S^T[32t x 32q] = K(th half) Q(qh)^T ; first MFMA consumes Zv as C
      bf16x8 kf0 = asbf(*(const u16x8*)&SM[0][qfro[0]]);
      __builtin_amdgcn_s_setprio(1);
      f32x16 s = __builtin_amdgcn_mfma_f32_32x32x16_bf16(kf0, bq[0], Zv, 0, 0, 0);
#pragma unroll
      for (int ks = 1; ks < 4; ++ks) {
        bf16x8 kf = asbf(*(const u16x8*)&SM[0][qfro[ks]]);
        s = __builtin_amdgcn_mfma_f32_32x32x16_bf16(kf, bq[ks], s, 0, 0, 0);
      }
      __builtin_amdgcn_s_setprio(0);
      softpack16(s, l31, dg && (th == qh), l5, sl2, p);
    }

    // prefetch next tile (all threads; hides HBM latency under PV)
    if (tau < qi) {
      const int tn = (tau + 1) * 64;
      st[0] = *(const u16x8*)(pK + (size_t)tn * ND);
      st[1] = *(const u16x8*)(pK + (size_t)(tn + 32) * ND);
      st[2] = *(const u16x8*)(pV + tn);
      st[3] = *(const u16x8*)(pV + (size_t)32 * NT + tn);
    }

    if (act) {
      // O^T += V^T(d-halves) P^T(this wave's t-slice)
      __builtin_amdgcn_s_setprio(1);
#pragma unroll
      for (int kp = 0; kp < 2; ++kp) {
        bf16x8 v0 = asbf(*(const u16x8*)&SM[1][vfro[kp]]);
        bf16x8 v1 = asbf(*(const u16x8*)&SM[1][2048 + vfro[kp]]);
        o0 = __builtin_amdgcn_mfma_f32_32x32x16_bf16(v0, p[kp], o0, 0, 0, 0);
        o1 = __builtin_amdgcn_mfma_f32_32x32x16_bf16(v1, p[kp], o1, 0, 0, 0);
      }
      __builtin_amdgcn_s_setprio(0);
    }
  }

  // ---- epilogue: combine l5 halves, then th-pair waves via LDS park ----
  const float slv = sl2[0] + sl2[1];
  float l = slv + __shfl_xor(slv, 32);
  __syncthreads();                       // done reading SM as K/V
  float* PK = (float*)&SM[0][0];         // 16KB park: [64 rows][64 lanes] f32
  if (th == 0) {
#pragma unroll
    for (int r = 0; r < 16; ++r) PK[(qh * 32 + r) * 64 + lane] = o0[r];
#pragma unroll
    for (int r = 0; r < 16; ++r) PK[(qh * 32 + 16 + r) * 64 + lane] = o1[r];
    PL[qh][lane] = l;
  }
  __syncthreads();
  if (th == 1) {
#pragma unroll
    for (int r = 0; r < 16; ++r) o0[r] += PK[(qh * 32 + r) * 64 + lane];
#pragma unroll
    for (int r = 0; r < 16; ++r) o1[r] += PK[(qh * 32 + 16 + r) * 64 + lane];
    l += PL[qh][lane];
    const float inv = 1.f / l;
    u16* yrow = Y + (size_t)(b * NT + qg) * NC + h * 64;
#pragma unroll
    for (int dh = 0; dh < 2; ++dh) {
      const f32x16& o = dh ? o1 : o0;
#pragma unroll
      for (int rq = 0; rq < 4; ++rq) {
        const int d = dh * 32 + 8 * rq + 4 * l5;
        uint2 w;
        w.x = pkbf(o[rq * 4 + 0] * inv, o[rq * 4 + 1] * inv);
        w.y = pkbf(o[rq * 4 + 2] * inv, o[rq * 4 + 3] * inv);
        *(uint2*)&yrow[d] = w;
      }
    }
  }
}

extern "C" void kernel_launch(void* const* d_in, const int* in_sizes, int n_in,
                              void* d_out, int out_size, void* d_ws, size_t ws_size,
                              hipStream_t stream) {
  (void)in_sizes; (void)n_in; (void)out_size; (void)ws_size;
  const float* x = (const float*)d_in[0];
  const float* w_qkv = (const float*)d_in[1];
  const float* w_out = (const float*)d_in[2];
  float* out = (float*)d_out;

  u16* ws = (u16*)d_ws;
  const size_t XE = (size_t)NB * NT * NC;       // 6291456 elements
  u16* xb  = ws;
  u16* wqT = xb + XE;
  u16* woT = wqT + (size_t)3 * NC * NC;
  u16* Qb  = woT + (size_t)NC * NC;
  u16* Kb  = Qb + XE;
  u16* Vtb = Kb + XE;
  u16* yb  = Vtb + XE;

  k_pre<<<dim3(PRE_CAST_BLKS + PRE_TA_BLKS + PRE_TB_BLKS), 256, 0, stream>>>(
      x, xb, w_qkv, wqT, w_out, woT);
  k_gemm_bt<1><<<dim3(3 * NC / 128, NB * NT / 128), 256, 0, stream>>>(
      xb, wqT, NB * NT, 3 * NC, NC, Qb, Kb, Vtb, nullptr);
  k_attn<<<dim3((NB * NH) * 64), 256, 0, stream>>>(Qb, Kb, Vtb, yb);
  k_gemm_bt<0><<<dim3(NC / 128, NB * NT / 128), 256, 0, stream>>>(
      yb, woT, NB * NT, NC, NC, nullptr, nullptr, nullptr, out);
}

// Round 8
// 221.207 us; speedup vs baseline: 1.6148x; 1.0636x over previous
//
#include <hip/hip_runtime.h>
#include <stdint.h>
#include <stddef.h>

#define NB 2
#define NT 4096
#define NC 768
#define NH 12
#define ND 64

typedef unsigned short u16;
typedef __attribute__((ext_vector_type(2))) float f32x2;
typedef __attribute__((ext_vector_type(4))) float f32x4;
typedef __attribute__((ext_vector_type(16))) float f32x16;
typedef __attribute__((ext_vector_type(8))) unsigned short u16x8;
typedef __attribute__((ext_vector_type(4))) unsigned short u16x4;
typedef __attribute__((ext_vector_type(8))) __bf16 bf16x8;
typedef __attribute__((ext_vector_type(4))) unsigned int u32x4;

typedef __attribute__((address_space(1))) const unsigned int gu32;
typedef __attribute__((address_space(3))) unsigned int lu32;

__device__ __forceinline__ u16 f2bf(float f) {
  uint32_t u = __builtin_bit_cast(uint32_t, f);
  u += 0x7FFFu + ((u >> 16) & 1u);   // RTNE
  return (u16)(u >> 16);
}
__device__ __forceinline__ bf16x8 asbf(u16x8 v) { return __builtin_bit_cast(bf16x8, v); }

// pack two f32 -> two bf16, round-half-up: 3 VALU
__device__ __forceinline__ uint32_t pkbf(float a, float b) {
  uint32_t ua = __builtin_bit_cast(uint32_t, a) + 0x8000u;
  uint32_t ub = __builtin_bit_cast(uint32_t, b) + 0x8000u;
  return __builtin_amdgcn_perm(ub, ua, 0x07060302u);
}
// truncating pack (P only; numerator/denominator stay consistent): 1 VALU
__device__ __forceinline__ uint32_t pktr(float a, float b) {
  return __builtin_amdgcn_perm(__builtin_bit_cast(uint32_t, b),
                               __builtin_bit_cast(uint32_t, a), 0x07060302u);
}

#define GLDS(gsrc, ldst) __builtin_amdgcn_global_load_lds( \
    (gu32*)(gsrc), (lu32*)(ldst), 16, 0, 0)

// ------- merged preprocessing: cast(x) + transpose(w_qkv) + transpose(w_out)
#define PRE_CAST_BLKS 6144             // (NB*NT*NC/4)/256
#define PRE_TA_BX 72                   // 3*NC/32
#define PRE_TA_BLKS (72 * 24)
#define PRE_TB_BX 24                   // NC/32
#define PRE_TB_BLKS (24 * 24)
__global__ __launch_bounds__(256)
void k_pre(const float* __restrict__ x, u16* __restrict__ xb,
           const float* __restrict__ w_qkv, u16* __restrict__ wqT,
           const float* __restrict__ w_out, u16* __restrict__ woT) {
  __shared__ float tile[32][33];
  const int bid = blockIdx.x;
  const int tid = threadIdx.x;
  if (bid < PRE_CAST_BLKS) {
    int i = bid * 256 + tid;
    f32x4 v = ((const f32x4*)x)[i];
    u16x4 o;
    o[0] = f2bf(v[0]); o[1] = f2bf(v[1]); o[2] = f2bf(v[2]); o[3] = f2bf(v[3]);
    ((u16x4*)xb)[i] = o;
    return;
  }
  const float* in;
  u16* out;
  int R, Cn, bx, by;
  if (bid < PRE_CAST_BLKS + PRE_TA_BLKS) {
    int q = bid - PRE_CAST_BLKS;
    bx = q % PRE_TA_BX; by = q / PRE_TA_BX;
    in = w_qkv; out = wqT; R = NC; Cn = 3 * NC;
  } else {
    int q = bid - PRE_CAST_BLKS - PRE_TA_BLKS;
    bx = q % PRE_TB_BX; by = q / PRE_TB_BX;
    in = w_out; out = woT; R = NC; Cn = NC;
  }
  int c0 = bx * 32, r0 = by * 32;
  int tx = tid & 31, ty = tid >> 5;
  for (int i = ty; i < 32; i += 8)
    tile[i][tx] = in[(size_t)(r0 + i) * Cn + c0 + tx];
  __syncthreads();
  for (int i = ty; i < 32; i += 8)
    out[(size_t)(c0 + i) * R + r0 + tx] = f2bf(tile[tx][i]);
}

// -------- GEMM: C[M,N] = A[M,K] * Bt[N,K]^T  (m97 structure, BK=64) --------
// BK=64: 12 barrier-drain pairs at K=768 instead of 24, 32 MFMA per pair.
// Staging via global_load_lds dwordx4 into LINEAR LDS with T21 pre-swizzled
// SOURCE granule ((lane&7)^lr): LDS granule g of row r holds global chunk
// (g ^ (r&7)), so ds_read at granule (want ^ (lc&7)) is bank-conflict-FREE
// (lanes lc/lc+8 alias 2-way = free).  row&7 == lc&7 for all mi => one offset
// per ks serves all four fragments.  EPI==1 V-section transposes through SMEM
// and stores V^T as coalesced 256B segments (proven r7).
template <int EPI>
__global__ __launch_bounds__(256, 3)
void k_gemm_bt(const u16* __restrict__ A, const u16* __restrict__ Bt,
               int M, int N, int K,
               u16* __restrict__ o0, u16* __restrict__ o1, u16* __restrict__ o2,
               float* __restrict__ of) {
  __shared__ u16 SMEM[2 * 128 * 64];   // As | Bs (16KB each); epi reuse
  u16* As = SMEM;
  u16* Bs = SMEM + 8192;
  const int tid = threadIdx.x;
  const int wave = tid >> 6, lane = tid & 63, quad = lane >> 4, lc = lane & 15;
  const int wm = (wave & 1) * 64, wn = (wave >> 1) * 64;
  const int bm = blockIdx.y * 128, bn = blockIdx.x * 128;

  // staging: wave w, chunk c covers rows c*32 + w*8 + lr (lr = lane>>3)
  const int lr = lane >> 3;
  const int gsw = ((lane & 7) ^ lr) * 8;          // pre-swizzled source granule
  const int rB = wave * 8 + lr;
  const u16* gA = A + (size_t)(bm + rB) * K + gsw;
  const u16* gB = Bt + (size_t)(bn + rB) * K + gsw;
  u16* lA0 = &As[wave * 8 * 64];                  // + c*2048 ; lane*16B linear
  u16* lB0 = &Bs[wave * 8 * 64];

  f32x4 zv = {0.f, 0.f, 0.f, 0.f};
  f32x4 acc[4][4];
#pragma unroll
  for (int i = 0; i < 4; ++i)
#pragma unroll
    for (int j = 0; j < 4; ++j) acc[i][j] = zv;

  for (int k0 = 0; k0 < K; k0 += 64) {
    __syncthreads();                 // prev iter's frag reads complete
#pragma unroll
    for (int c = 0; c < 4; ++c) {
      GLDS(gA + (size_t)c * 32 * K + k0, lA0 + c * 2048);
      GLDS(gB + (size_t)c * 32 * K + k0, lB0 + c * 2048);
    }
    asm volatile("s_waitcnt vmcnt(0)" ::: "memory");
    __syncthreads();                 // all waves' DMA landed

#pragma unroll
    for (int ks = 0; ks < 2; ++ks) {
      const int ao = (((ks << 2) + quad) ^ (lc & 7)) * 8;   // swizzled granule
      bf16x8 af[4], bfv[4];
#pragma unroll
      for (int mi = 0; mi < 4; ++mi)
        af[mi] = asbf(*(const u16x8*)&As[(wm + mi * 16 + lc) * 64 + ao]);
#pragma unroll
      for (int ni = 0; ni < 4; ++ni)
        bfv[ni] = asbf(*(const u16x8*)&Bs[(wn + ni * 16 + lc) * 64 + ao]);
#pragma unroll
      for (int mi = 0; mi < 4; ++mi)
#pragma unroll
        for (int ni = 0; ni < 4; ++ni)
          acc[mi][ni] = __builtin_amdgcn_mfma_f32_16x16x32_bf16(af[mi], bfv[ni],
                                                                acc[mi][ni], 0, 0, 0);
    }
  }

  const int sect = (EPI == 1) ? (bn / NC) : 0;   // block-uniform
  if (EPI == 1 && sect == 2) {
    // ---- V^T transposed epilogue through SMEM ----
    const int b = bm >> 12;
    const int tb = bm & (NT - 1);
    const int hb = (bn - 2 * NC) >> 6;
#pragma unroll 1
    for (int r2_ = 0; r2_ < 2; ++r2_) {
      __syncthreads();               // SMEM free / prev half read out
      if ((wave >> 1) == r2_) {      // waves owning wn == 64*r2_
#pragma unroll
        for (int mi = 0; mi < 4; ++mi)
#pragma unroll
          for (int ni = 0; ni < 4; ++ni) {
            const int nl = ni * 16 + lc;          // n within this 64-col half
#pragma unroll
            for (int r = 0; r < 4; ++r) {
              const int m = wm + mi * 16 + quad * 4 + r;
              SMEM[nl * 128 + (m ^ ((nl & 7) << 3))] = f2bf(acc[mi][ni][r]);
            }
          }
      }
      __syncthreads();
#pragma unroll
      for (int pass = 0; pass < 4; ++pass) {
        const int row = (tid >> 4) + 16 * pass;   // d-row within half
        const int chunk = tid & 15;               // 8-elem t-chunk
        u16x8 w = *(const u16x8*)&SMEM[row * 128 + ((chunk ^ (row & 7)) * 8)];
        const int nl = 64 * r2_ + row;
        *(u16x8*)&o2[((size_t)(b * NH + hb + (nl >> 6)) * ND + (nl & 63)) * NT
                     + tb + chunk * 8] = w;
      }
    }
    return;
  }

  const int mrow0 = bm + wm + quad * 4;
#pragma unroll
  for (int mi = 0; mi < 4; ++mi) {
    const int mbase = mrow0 + mi * 16;
#pragma unroll
    for (int ni = 0; ni < 4; ++ni) {
      const int n = bn + wn + ni * 16 + lc;
      if (EPI == 0) {
#pragma unroll
        for (int r = 0; r < 4; ++r)
          of[(size_t)(mbase + r) * N + n] = acc[mi][ni][r];
      } else {
        const int wn2 = n - sect * NC;
        const int h = wn2 >> 6, d = wn2 & 63;
        const int b = mbase >> 12;
        const int t = mbase & (NT - 1);
        const float sc = (sect == 0) ? 0.18033688011112042f : 1.0f;  // log2e/8
        u16* dst = (sect == 0) ? o0 : o1;
#pragma unroll
        for (int r = 0; r < 4; ++r)
          dst[((size_t)(b * NH + h) * NT + (t + r)) * ND + d] =
              f2bf(acc[mi][ni][r] * sc);
      }
    }
  }
}

// ============ flash attention (r2 structure): causal, 32x32x16, wave-split ==
// Grid = 24 bh x 64 q-tiles (descending qi: long blocks dispatch first).
// Block = 4 waves (qh = wave&1, th = wave>>1): each wave computes a 32q x 32t
// sub-tile per K/V tile.  No online rescale => t-tiles independent => th-pair
// waves hold partial O/l in registers and combine ONCE via LDS at epilogue.
// P stays in registers: S^T cols are lane-local (32x32 C layout), repacked to
// the PV B-operand with pktr + permlane32_swap.
// LDS: single 16KB K/V tile, XOR-swizzled (granule ^= row&7), reused as the
// epilogue park area.  Denominator = in-lane sum of TRUNCATED exp (consistent
// with bf16 P) + shfl_xor(32) + cross-wave add.
// This round: exp2 via __builtin_amdgcn_exp2f (raw v_exp_f32 — bypasses any
// __ocml range-check wrapper; the kernel is trans/VALU-issue-bound).
__device__ __forceinline__ void softpack16(const f32x16& s, int qrel, bool msk,
                                           int l5, f32x2& sl2, bf16x8* pf) {
  float e[16];
#pragma unroll
  for (int r = 0; r < 16; ++r) {
    float v = s[r];
    if (msk) {
      int tl = (r & 3) + 8 * (r >> 2) + 4 * l5;   // 32x32 C-layout row
      v = (tl > qrel) ? -1e30f : v;
    }
    e[r] = __builtin_amdgcn_exp2f(v);
  }
  uint32_t wv[8];
#pragma unroll
  for (int i = 0; i < 8; ++i) {
    wv[i] = pktr(e[2 * i], e[2 * i + 1]);
    // denominator from the SAME truncated bf16 values the numerator uses
    f32x2 inc = {__builtin_bit_cast(float, wv[i] & 0xFFFF0000u),
                 __builtin_bit_cast(float, wv[i] << 16)};
    sl2 += inc;
  }
  // B-frag g covers t_local = g*16 + l5*8 + j; half-exchange = permlane32_swap
#pragma unroll
  for (int g = 0; g < 2; ++g) {
    auto r0 = __builtin_amdgcn_permlane32_swap(wv[g * 4 + 0], wv[g * 4 + 2], false, false);
    auto r1 = __builtin_amdgcn_permlane32_swap(wv[g * 4 + 1], wv[g * 4 + 3], false, false);
    u32x4 f = {r0[0], r1[0], r0[1], r1[1]};
    pf[g] = __builtin_bit_cast(bf16x8, f);
  }
}

__global__ __launch_bounds__(256, 3)
void k_attn(const u16* __restrict__ Q, const u16* __restrict__ K,
            const u16* __restrict__ Vt, u16* __restrict__ Y) {
  __shared__ u16 SM[2][64 * 64];   // [0]=K tile [t][d], [1]=V^T tile [d][t]
  __shared__ float PL[2][64];      // l park
  const int tid = threadIdx.x;
  const int lane = tid & 63, wave = tid >> 6;
  const int l5 = lane >> 5, l31 = lane & 31;
  const int qh = wave & 1, th = wave >> 1;
  const int bh = blockIdx.x % (NB * NH);
  const int qi = 63 - blockIdx.x / (NB * NH);      // long blocks first
  const int b = bh / NH, h = bh - b * NH;
  const u16* __restrict__ Qb = Q + (size_t)bh * NT * ND;
  const u16* __restrict__ Kb = K + (size_t)bh * NT * ND;
  const u16* __restrict__ Vb = Vt + (size_t)bh * (size_t)ND * NT;

  const int qg = qi * 64 + qh * 32 + l31;          // this lane's q column

  // Q as B-operand frags: col q = l31(+qh*32), k(d) = ks*16 + l5*8 + j
  bf16x8 bq[4];
#pragma unroll
  for (int ks = 0; ks < 4; ++ks)
    bq[ks] = asbf(*(const u16x8*)(Qb + (size_t)qg * ND + ks * 16 + l5 * 8));

  f32x16 Zv;
#pragma unroll
  for (int i = 0; i < 16; ++i) Zv[i] = 0.f;
  f32x16 o0 = Zv, o1 = Zv;     // O^T partial (d-halves), this wave's (qh,th)
  f32x2 sl2 = {0.f, 0.f};      // truncation-consistent partial l (2 lanes)

  // staging: 256 thr x 4 x 16B = 16KB/iter; dest XOR-swizzled
  const int srow = tid >> 3, sg = tid & 7;
  const int soff = srow * 64 + ((sg ^ (srow & 7)) * 8);
  const u16* __restrict__ pK = Kb + (size_t)srow * ND + sg * 8;
  const u16* __restrict__ pV = Vb + (size_t)srow * NT + sg * 8;

  // LDS frag offsets (elements), matching XOR swizzle
  int qfro[4];
#pragma unroll
  for (int ks = 0; ks < 4; ++ks)
    qfro[ks] = (th * 32 + l31) * 64 + (((ks * 2 + l5) ^ (l31 & 7)) * 8);
  int vfro[2];
#pragma unroll
  for (int kp = 0; kp < 2; ++kp)
    vfro[kp] = l31 * 64 + ((((2 * th + kp) * 2 + l5) ^ (l31 & 7)) * 8);

  // prefetch tile 0
  u16x8 st[4];
  st[0] = *(const u16x8*)(pK);
  st[1] = *(const u16x8*)(pK + (size_t)32 * ND);
  st[2] = *(const u16x8*)(pV);
  st[3] = *(const u16x8*)(pV + (size_t)32 * NT);

#pragma unroll 1
  for (int tau = 0; tau <= qi; ++tau) {
    __syncthreads();
    *(u16x8*)&SM[0][soff] = st[0];
    *(u16x8*)&SM[0][2048 + soff] = st[1];
    *(u16x8*)&SM[1][soff] = st[2];
    *(u16x8*)&SM[1][2048 + soff] = st[3];
    __syncthreads();

    const bool dg = (tau == qi);
    const bool act = !(dg && th > qh);    // wave-uniform
    bf16x8 p[2];
    if (act) {
      // S^T[32t x 32q] = K(th half) Q(qh)^T ; first MFMA consumes Zv as C
      bf16x8 kf0 = asbf(*(const u16x8*)&SM[0][qfro[0]]);
      __builtin_amdgcn_s_setprio(1);
      f32x16 s = __builtin_amdgcn_mfma_f32_32x32x16_bf16(kf0, bq[0], Zv, 0, 0, 0);
#pragma unroll
      for (int ks = 1; ks < 4; ++ks) {
        bf16x8 kf = asbf(*(const u16x8*)&SM[0][qfro[ks]]);
        s = __builtin_amdgcn_mfma_f32_32x32x16_bf16(kf, bq[ks], s, 0, 0, 0);
      }
      __builtin_amdgcn_s_setprio(0);
      softpack16(s, l31, dg && (th == qh), l5, sl2, p);
    }

    // prefetch next tile (all threads; hides HBM latency under PV)
    if (tau < qi) {
      const int tn = (tau + 1) * 64;
      st[0] = *(const u16x8*)(pK + (size_t)tn * ND);
      st[1] = *(const u16x8*)(pK + (size_t)(tn + 32) * ND);
      st[2] = *(const u16x8*)(pV + tn);
      st[3] = *(const u16x8*)(pV + (size_t)32 * NT + tn);
    }

    if (act) {
      // O^T += V^T(d-halves) P^T(this wave's t-slice)
      __builtin_amdgcn_s_setprio(1);
#pragma unroll
      for (int kp = 0; kp < 2; ++kp) {
        bf16x8 v0 = asbf(*(const u16x8*)&SM[1][vfro[kp]]);
        bf16x8 v1 = asbf(*(const u16x8*)&SM[1][2048 + vfro[kp]]);
        o0 = __builtin_amdgcn_mfma_f32_32x32x16_bf16(v0, p[kp], o0, 0, 0, 0);
        o1 = __builtin_amdgcn_mfma_f32_32x32x16_bf16(v1, p[kp], o1, 0, 0, 0);
      }
      __builtin_amdgcn_s_setprio(0);
    }
  }

  // ---- epilogue: combine l5 halves, then th-pair waves via LDS park ----
  const float slv = sl2[0] + sl2[1];
  float l = slv + __shfl_xor(slv, 32);
  __syncthreads();                       // done reading SM as K/V
  float* PK = (float*)&SM[0][0];         // 16KB park: [64 rows][64 lanes] f32
  if (th == 0) {
#pragma unroll
    for (int r = 0; r < 16; ++r) PK[(qh * 32 + r) * 64 + lane] = o0[r];
#pragma unroll
    for (int r = 0; r < 16; ++r) PK[(qh * 32 + 16 + r) * 64 + lane] = o1[r];
    PL[qh][lane] = l;
  }
  __syncthreads();
  if (th == 1) {
#pragma unroll
    for (int r = 0; r < 16; ++r) o0[r] += PK[(qh * 32 + r) * 64 + lane];
#pragma unroll
    for (int r = 0; r < 16; ++r) o1[r] += PK[(qh * 32 + 16 + r) * 64 + lane];
    l += PL[qh][lane];
    const float inv = 1.f / l;
    u16* yrow = Y + (size_t)(b * NT + qg) * NC + h * 64;
#pragma unroll
    for (int dh = 0; dh < 2; ++dh) {
      const f32x16& o = dh ? o1 : o0;
#pragma unroll
      for (int rq = 0; rq < 4; ++rq) {
        const int d = dh * 32 + 8 * rq + 4 * l5;
        uint2 w;
        w.x = pkbf(o[rq * 4 + 0] * inv, o[rq * 4 + 1] * inv);
        w.y = pkbf(o[rq * 4 + 2] * inv, o[rq * 4 + 3] * inv);
        *(uint2*)&yrow[d] = w;
      }
    }
  }
}

extern "C" void kernel_launch(void* const* d_in, const int* in_sizes, int n_in,
                              void* d_out, int out_size, void* d_ws, size_t ws_size,
                              hipStream_t stream) {
  (void)in_sizes; (void)n_in; (void)out_size; (void)ws_size;
  const float* x = (const float*)d_in[0];
  const float* w_qkv = (const float*)d_in[1];
  const float* w_out = (const float*)d_in[2];
  float* out = (float*)d_out;

  u16* ws = (u16*)d_ws;
  const size_t XE = (size_t)NB * NT * NC;       // 6291456 elements
  u16* xb  = ws;
  u16* wqT = xb + XE;
  u16* woT = wqT + (size_t)3 * NC * NC;
  u16* Qb  = woT + (size_t)NC * NC;
  u16* Kb  = Qb + XE;
  u16* Vtb = Kb + XE;
  u16* yb  = Vtb + XE;

  k_pre<<<dim3(PRE_CAST_BLKS + PRE_TA_BLKS + PRE_TB_BLKS), 256, 0, stream>>>(
      x, xb, w_qkv, wqT, w_out, woT);
  k_gemm_bt<1><<<dim3(3 * NC / 128, NB * NT / 128), 256, 0, stream>>>(
      xb, wqT, NB * NT, 3 * NC, NC, Qb, Kb, Vtb, nullptr);
  k_attn<<<dim3((NB * NH) * 64), 256, 0, stream>>>(Qb, Kb, Vtb, yb);
  k_gemm_bt<0><<<dim3(NC / 128, NB * NT / 128), 256, 0, stream>>>(
      yb, woT, NB * NT, NC, NC, nullptr, nullptr, nullptr, out);
}